// Round 9
// baseline (76.327 us; speedup 1.0000x reference)
//
#include <hip/hip_runtime.h>

#define C_IN     7
#define D_MODEL  512
#define TAO      3
#define M_TAPS   5
#define KERNELS  73            // D_MODEL / C_IN
#define B_SZ     32
#define L_SZ     4096
#define TB       64            // t-positions per block
#define NTB      (L_SZ / TB)   // 64
#define ROWS     (TB + 17)     // 81 staged rows
#define RPAD     84
#define CHUNK    8             // t-rows per chunk (win[25], spill-safe)

__global__ __launch_bounds__(256, 2) void trc_conv_kernel(
    const float* __restrict__ x,          // [B, L, C_IN]
    const float* __restrict__ conv_w,     // [73, 6, 3]
    const float* __restrict__ conv_b,     // [73]
    const float* __restrict__ leftout_w,  // [1, 6, 3]
    const float* __restrict__ leftout_b,  // [1]
    float* __restrict__ out)              // [B, L, 512]
{
    __shared__ float xs[C_IN][RPAD];
    const int tid = threadIdx.x;
    const int b   = blockIdx.x / NTB;
    const int tb  = blockIdx.x % NTB;
    const int t0  = tb * TB;

    // Stage x rows [t0-16, t0+TB] (circular) into LDS, transposed [ch][row].
    const float* xb = x + (size_t)b * L_SZ * C_IN;
    for (int i = tid; i < ROWS * C_IN; i += 256) {
        int r = i / C_IN, c = i - r * C_IN;
        int g = t0 - 16 + r;
        if (g < 0)      g += L_SZ;
        if (g >= L_SZ)  g -= L_SZ;
        xs[c][r] = xb[(size_t)g * C_IN + c];
    }
    __syncthreads();   // only barrier

    // Thread owns adjacent pair d0 = 2*tid, d1 = d0+1 (float2 store).
    const int d0 = 2 * tid, d1 = d0 + 1;

    int ch0, ch1;
    const float *ws0, *ws1;
    float bias0, bias1;
    if (d0 < C_IN * KERNELS) { ch0 = d0 / KERNELS; int o = d0 - ch0 * KERNELS; ws0 = conv_w + o * 18; bias0 = conv_b[o]; }
    else                     { ch0 = C_IN - 1; ws0 = leftout_w; bias0 = leftout_b[0]; }
    if (d1 < C_IN * KERNELS) { ch1 = d1 / KERNELS; int o = d1 - ch1 * KERNELS; ws1 = conv_w + o * 18; bias1 = conv_b[o]; }
    else                     { ch1 = C_IN - 1; ws1 = leftout_w; bias1 = leftout_b[0]; }

    const float* __restrict__ rowA = &xs[ch0][0];
    const float* __restrict__ rowB = &xs[ch1][0];

    // FIR weights by row-offset j (0 = oldest = row t-16): k=j%3, m=(15+k-j)/3.
    float wa[18], wb[18];
    #pragma unroll
    for (int j = 0; j < 18; ++j) {
        int k = j % 3;
        int m = (15 + k - j) / 3;
        wa[j] = ws0[m * 3 + k];
        wb[j] = ws1[m * 3 + k];
    }

    float2* outv = (float2*)(out + ((size_t)b * L_SZ + t0) * D_MODEL) + tid;

    if (tb == 0 || tb == NTB - 1) {
        // Edge blocks (2/64 of tb positions): masked path, direct LDS reads,
        // no register arrays -> no spill risk here.
        for (int tl = 0; tl < TB; ++tl) {
            float a0 = bias0, a1 = bias1;
            #pragma unroll
            for (int k = 0; k < 3; ++k) {
                int tt = t0 + tl + k - 1;
                if (tt < 0)      tt += L_SZ;
                if (tt >= L_SZ)  tt -= L_SZ;
                if (tt >= M_TAPS * TAO) {
                    int lt = tl + 15 + k;
                    #pragma unroll
                    for (int m = 0; m < 6; ++m) {
                        a0 = fmaf(rowA[lt - 3 * m], wa[15 + k - 3 * m], a0);
                        a1 = fmaf(rowB[lt - 3 * m], wb[15 + k - 3 * m], a1);
                    }
                }
            }
            outv[(size_t)tl * (D_MODEL / 2)] = make_float2(a0, a1);
        }
        return;
    }

    // Interior: dual static windows (chunk=8, win[25] -> ~105 live VGPRs,
    // under the 128 cap), direct float2 stores, no barriers, no LDS roundtrip.
    float winA[25], winB[25];
    #pragma unroll
    for (int q = 0; q < 17; ++q) { winA[q] = rowA[q]; winB[q] = rowB[q]; }

    for (int c = 0; c < TB; c += CHUNK) {
        #pragma unroll
        for (int i = 0; i < CHUNK; ++i) {
            winA[17 + i] = rowA[c + 17 + i];
            winB[17 + i] = rowB[c + 17 + i];
        }
        #pragma unroll
        for (int i = 0; i < CHUNK; ++i) {
            float a0 = bias0, a1 = bias1;
            #pragma unroll
            for (int j = 0; j < 18; ++j) {
                a0 = fmaf(winA[i + j], wa[j], a0);
                a1 = fmaf(winB[i + j], wb[j], a1);
            }
            outv[(size_t)(c + i) * (D_MODEL / 2)] = make_float2(a0, a1);
        }
        #pragma unroll
        for (int q = 0; q < 17; ++q) { winA[q] = winA[q + CHUNK]; winB[q] = winB[q + CHUNK]; }
    }
}

extern "C" void kernel_launch(void* const* d_in, const int* in_sizes, int n_in,
                              void* d_out, int out_size, void* d_ws, size_t ws_size,
                              hipStream_t stream) {
    const float* x          = (const float*)d_in[0];
    const float* conv_w     = (const float*)d_in[1];
    const float* conv_b     = (const float*)d_in[2];
    const float* leftout_w  = (const float*)d_in[3];
    const float* leftout_b  = (const float*)d_in[4];
    float* out = (float*)d_out;

    dim3 grid(B_SZ * NTB);   // 2048 blocks x 256 threads
    trc_conv_kernel<<<grid, 256, 0, stream>>>(x, conv_w, conv_b,
                                              leftout_w, leftout_b, out);
}

// Round 10
// 66.806 us; speedup vs baseline: 1.1425x; 1.1425x over previous
//
#include <hip/hip_runtime.h>

#define C_IN     7
#define D_MODEL  512
#define TAO      3
#define M_TAPS   5
#define KERNELS  73            // D_MODEL / C_IN
#define B_SZ     32
#define L_SZ     4096
#define TB       32            // t-positions per block
#define NTB      (L_SZ / TB)   // 128
#define ROWS     (TB + 17)     // 49 staged rows
#define RPAD     52
#define CHUNK    8
#define NCH      (TB / CHUNK)  // 4

__global__ __launch_bounds__(512, 2) void trc_conv_kernel(
    const float* __restrict__ x,          // [B, L, C_IN]
    const float* __restrict__ conv_w,     // [73, 6, 3]
    const float* __restrict__ conv_b,     // [73]
    const float* __restrict__ leftout_w,  // [1, 6, 3]
    const float* __restrict__ leftout_b,  // [1]
    float* __restrict__ out)              // [B, L, 512]
{
    __shared__ float xs[C_IN][RPAD];
    __shared__ __align__(16) float buf[TB][D_MODEL];   // 64 KB out-tile (transpose)

    const int tid = threadIdx.x;
    const int b   = blockIdx.x / NTB;
    const int tb  = blockIdx.x % NTB;
    const int t0  = tb * TB;

    // Stage x rows [t0-16, t0+TB] (circular) into LDS, transposed [ch][row].
    const float* xb = x + (size_t)b * L_SZ * C_IN;
    if (tid < ROWS * C_IN) {
        int r = tid / C_IN, c = tid - r * C_IN;
        int g = t0 - 16 + r;
        if (g < 0)      g += L_SZ;
        if (g >= L_SZ)  g -= L_SZ;
        xs[c][r] = xb[(size_t)g * C_IN + c];
    }
    __syncthreads();

    // Column ownership: d = tid. ch = d/73, o = d%73 (d==511 -> leftout).
    const int d = tid;
    int ch;
    const float* wsrc;
    float bias;
    if (d < C_IN * KERNELS) {
        ch = d / KERNELS;
        int o = d - ch * KERNELS;
        wsrc = conv_w + o * 18;
        bias = conv_b[o];
    } else {
        ch = C_IN - 1;
        wsrc = leftout_w;
        bias = leftout_b[0];
    }
    const float* __restrict__ row = &xs[ch][0];

    // FIR weights by row-offset j (0 = oldest = row t-16): k=j%3, m=(15+k-j)/3.
    float wreg[18];
    #pragma unroll
    for (int j = 0; j < 18; ++j) {
        int k = j % 3;
        int m = (15 + k - j) / 3;
        wreg[j] = wsrc[m * 3 + k];
    }

    if (tb == 0 || tb == NTB - 1) {
        // Edge blocks (2/128): masked path (wrap + validity), direct LDS reads.
        for (int tl = 0; tl < TB; ++tl) {
            float acc = bias;
            #pragma unroll
            for (int k = 0; k < 3; ++k) {
                int tt = t0 + tl + k - 1;
                if (tt < 0)      tt += L_SZ;
                if (tt >= L_SZ)  tt -= L_SZ;
                if (tt >= M_TAPS * TAO) {
                    int lt = tl + 15 + k;
                    #pragma unroll
                    for (int m = 0; m < 6; ++m)
                        acc = fmaf(row[lt - 3 * m], wreg[15 + k - 3 * m], acc);
                }
            }
            buf[tl][d] = acc;
        }
    } else {
        // Interior: sliding window (static indices), 4 chunks of 8 rows,
        // write the transpose tile (stride-1 across lanes: conflict-free).
        float win[25];
        #pragma unroll
        for (int q = 0; q < 17; ++q) win[q] = row[q];

        for (int c = 0; c < NCH; ++c) {
            #pragma unroll
            for (int i = 0; i < CHUNK; ++i) win[17 + i] = row[c * CHUNK + 17 + i];
            #pragma unroll
            for (int i = 0; i < CHUNK; ++i) {
                float acc = bias;
                #pragma unroll
                for (int j = 0; j < 18; ++j)
                    acc = fmaf(win[i + j], wreg[j], acc);
                buf[c * CHUNK + i][d] = acc;
            }
            #pragma unroll
            for (int q = 0; q < 17; ++q) win[q] = win[q + CHUNK];
        }
    }

    // LDS-only barrier (no vmcnt drain).
    __builtin_amdgcn_sched_barrier(0);
    asm volatile("s_waitcnt lgkmcnt(0)" ::: "memory");
    __builtin_amdgcn_sched_barrier(0);
    __builtin_amdgcn_s_barrier();
    __builtin_amdgcn_sched_barrier(0);

    // Terminal store burst: read 8 float4 from the tile, then 8 back-to-back
    // dwordx4 stores covering the block's sequential 64 KB; s_endpgm with
    // stores in flight (no WAR reuse, no drains).
    const float4* bv = (const float4*)&buf[0][0];
    float4 v0 = bv[tid];
    float4 v1 = bv[tid + 512];
    float4 v2 = bv[tid + 1024];
    float4 v3 = bv[tid + 1536];
    float4 v4 = bv[tid + 2048];
    float4 v5 = bv[tid + 2560];
    float4 v6 = bv[tid + 3072];
    float4 v7 = bv[tid + 3584];

    float4* o4 = (float4*)(out + ((size_t)b * L_SZ + t0) * D_MODEL);
    o4[tid]        = v0;
    o4[tid + 512]  = v1;
    o4[tid + 1024] = v2;
    o4[tid + 1536] = v3;
    o4[tid + 2048] = v4;
    o4[tid + 2560] = v5;
    o4[tid + 3072] = v6;
    o4[tid + 3584] = v7;
}

extern "C" void kernel_launch(void* const* d_in, const int* in_sizes, int n_in,
                              void* d_out, int out_size, void* d_ws, size_t ws_size,
                              hipStream_t stream) {
    const float* x          = (const float*)d_in[0];
    const float* conv_w     = (const float*)d_in[1];
    const float* conv_b     = (const float*)d_in[2];
    const float* leftout_w  = (const float*)d_in[3];
    const float* leftout_b  = (const float*)d_in[4];
    float* out = (float*)d_out;

    dim3 grid(B_SZ * NTB);   // 4096 blocks x 512 threads
    trc_conv_kernel<<<grid, 512, 0, stream>>>(x, conv_w, conv_b,
                                              leftout_w, leftout_b, out);
}